// Round 8
// baseline (639.788 us; speedup 1.0000x reference)
//
#include <hip/hip_runtime.h>

#define NB   65536
#define HID  512
#define MID  256
#define PROJ 128
#define KNEG 8
#define TEMP_INV (1.0f/0.07f)

typedef __attribute__((ext_vector_type(8))) short bf16x8;
typedef __attribute__((ext_vector_type(4))) float f32x4;

#define A_STR 136   // chunk of 128 k + 8 pad (shorts)
#define H_STR 264   // 256 + 8 pad (shorts)
#define P_STR 132   // 128 + 4 pad (floats)

__device__ __forceinline__ short f2bf(float x) {
    unsigned u = __float_as_uint(x);
    unsigned r = (u + 0x7fffu + ((u >> 16) & 1u)) >> 16;   // RNE
    return (short)r;
}
__device__ __forceinline__ float bf2f(short h) {
    return __uint_as_float(((unsigned)(unsigned short)h) << 16);
}

// ---------------------------------------------------------------------------
// Weight prep: W [K][N] fp32 -> WT hi/lo bf16 [N][K] (K-contiguous)
// ---------------------------------------------------------------------------
__global__ void prep_w_kernel(const float* __restrict__ W, short* __restrict__ hi,
                              short* __restrict__ lo, int N, int Kshift, int total)
{
    int idx = blockIdx.x * 256 + threadIdx.x;
    if (idx >= total) return;
    int n = idx >> Kshift;
    int k = idx & ((1 << Kshift) - 1);
    float x = W[(size_t)k * N + n];
    short h = f2bf(x);
    short l = f2bf(x - bf2f(h));
    hi[idx] = h;
    lo[idx] = l;
}

// ---------------------------------------------------------------------------
// Fused projection via MFMA bf16x3 (hi*hi + hi*lo + lo*hi)
// pool[2B][128] = L2norm( LN( relu(X@W1+b1) @ W2 + b2 ) )
// LDS: 33.8 KB union buffer (A-chunk / H / P overlay) -> 4 blocks/CU
// ---------------------------------------------------------------------------
__global__ __launch_bounds__(256, 4)
void proj_mfma(const float* __restrict__ hs, const float* __restrict__ ph,
               const short* __restrict__ w1h, const short* __restrict__ w1l,
               const short* __restrict__ w2h, const short* __restrict__ w2l,
               const float* __restrict__ b1, const float* __restrict__ b2,
               const float* __restrict__ gam, const float* __restrict__ bet,
               float* __restrict__ pool)
{
    __shared__ float smem[8448];                // 33,792 B
    short* Ahi = (short*)smem;                  // [32][136] chunk (8704 B)
    short* Alo = Ahi + 32 * A_STR;              // [32][136]
    short* Hhi = (short*)smem;                  // [32][264] (overlays A)
    short* Hlo = Hhi + 32 * H_STR;
    float* P   = smem;                          // [32][132] (overlays H)

    const int tid  = threadIdx.x;
    const int w    = tid >> 6;                  // wave 0..3
    const int lane = tid & 63;
    const int l16  = lane & 15;
    const int g    = lane >> 4;                 // 0..3
    const int row0 = blockIdx.x * 32;
    const float* __restrict__ X = (row0 < NB) ? (hs + (size_t)row0 * HID)
                                              : (ph + (size_t)(row0 - NB) * HID);

    // b1 fragment (col = w*64 + nb*16 + l16)
    float b1v[4];
    #pragma unroll
    for (int nb = 0; nb < 4; ++nb) b1v[nb] = b1[w * 64 + nb * 16 + l16];

    // -------- GEMM1: [32][512] @ W1T[256][512], A staged in 4 K-chunks --------
    f32x4 acc[2][4];
    #pragma unroll
    for (int mb = 0; mb < 2; ++mb)
        #pragma unroll
        for (int nb = 0; nb < 4; ++nb) acc[mb][nb] = (f32x4){0.f, 0.f, 0.f, 0.f};

    const int koff = g * 8;
    for (int c = 0; c < 4; ++c) {
        __syncthreads();                        // previous chunk's reads done
        // stage & split A chunk [32][128]: 4 float4 per thread
        #pragma unroll
        for (int i = 0; i < 4; ++i) {
            const int f = i * 256 + tid;        // float4 index
            const int r = f >> 5, c4 = (f & 31) * 4;
            float4 v = *reinterpret_cast<const float4*>(X + (size_t)r * HID + c * 128 + c4);
            float xv[4] = {v.x, v.y, v.z, v.w};
            short hh[4], ll[4];
            #pragma unroll
            for (int j = 0; j < 4; ++j) {
                hh[j] = f2bf(xv[j]);
                ll[j] = f2bf(xv[j] - bf2f(hh[j]));
            }
            *reinterpret_cast<short4*>(Ahi + r * A_STR + c4) = make_short4(hh[0], hh[1], hh[2], hh[3]);
            *reinterpret_cast<short4*>(Alo + r * A_STR + c4) = make_short4(ll[0], ll[1], ll[2], ll[3]);
        }
        __syncthreads();                        // chunk staged

        #pragma unroll
        for (int t = 0; t < 4; ++t) {
            const int kl = t * 32 + koff;       // k within chunk
            const int kg = c * 128 + kl;        // global k
            bf16x8 a_h[2], a_l[2], b_h[4], b_l[4];
            #pragma unroll
            for (int mb = 0; mb < 2; ++mb) {
                const int ro = (mb * 16 + l16) * A_STR + kl;
                a_h[mb] = *reinterpret_cast<const bf16x8*>(Ahi + ro);
                a_l[mb] = *reinterpret_cast<const bf16x8*>(Alo + ro);
            }
            #pragma unroll
            for (int nb = 0; nb < 4; ++nb) {
                const size_t co = (size_t)(w * 64 + nb * 16 + l16) * 512 + kg;
                b_h[nb] = *reinterpret_cast<const bf16x8*>(w1h + co);
                b_l[nb] = *reinterpret_cast<const bf16x8*>(w1l + co);
            }
            #pragma unroll
            for (int mb = 0; mb < 2; ++mb)
                #pragma unroll
                for (int nb = 0; nb < 4; ++nb) {
                    acc[mb][nb] = __builtin_amdgcn_mfma_f32_16x16x32_bf16(a_h[mb], b_h[nb], acc[mb][nb], 0, 0, 0);
                    acc[mb][nb] = __builtin_amdgcn_mfma_f32_16x16x32_bf16(a_h[mb], b_l[nb], acc[mb][nb], 0, 0, 0);
                    acc[mb][nb] = __builtin_amdgcn_mfma_f32_16x16x32_bf16(a_l[mb], b_h[nb], acc[mb][nb], 0, 0, 0);
                }
        }
    }

    __syncthreads();   // all GEMM1 A-reads done; region reused for H

    // -------- H = relu(acc + b1) -> Hhi/Hlo (C/D: col=lane&15, row=g*4+reg) --------
    #pragma unroll
    for (int mb = 0; mb < 2; ++mb)
        #pragma unroll
        for (int nb = 0; nb < 4; ++nb) {
            const int col = w * 64 + nb * 16 + l16;
            #pragma unroll
            for (int r = 0; r < 4; ++r) {
                const int row = mb * 16 + g * 4 + r;
                float hval = fmaxf(acc[mb][nb][r] + b1v[nb], 0.f);
                short hh = f2bf(hval);
                short hl = f2bf(hval - bf2f(hh));
                Hhi[row * H_STR + col] = hh;
                Hlo[row * H_STR + col] = hl;
            }
        }

    __syncthreads();

    // -------- GEMM2: H[32][256] @ W2T[128][256] -> acc2[2][2] --------
    f32x4 acc2[2][2];
    #pragma unroll
    for (int mb = 0; mb < 2; ++mb)
        #pragma unroll
        for (int nb = 0; nb < 2; ++nb) acc2[mb][nb] = (f32x4){0.f, 0.f, 0.f, 0.f};

    #pragma unroll
    for (int t = 0; t < 8; ++t) {
        const int k0 = t * 32 + koff;
        bf16x8 a_h[2], a_l[2], b_h[2], b_l[2];
        #pragma unroll
        for (int mb = 0; mb < 2; ++mb) {
            const int ro = (mb * 16 + l16) * H_STR + k0;
            a_h[mb] = *reinterpret_cast<const bf16x8*>(Hhi + ro);
            a_l[mb] = *reinterpret_cast<const bf16x8*>(Hlo + ro);
        }
        #pragma unroll
        for (int nb = 0; nb < 2; ++nb) {
            const size_t co = (size_t)(w * 32 + nb * 16 + l16) * 256 + k0;
            b_h[nb] = *reinterpret_cast<const bf16x8*>(w2h + co);
            b_l[nb] = *reinterpret_cast<const bf16x8*>(w2l + co);
        }
        #pragma unroll
        for (int mb = 0; mb < 2; ++mb)
            #pragma unroll
            for (int nb = 0; nb < 2; ++nb) {
                acc2[mb][nb] = __builtin_amdgcn_mfma_f32_16x16x32_bf16(a_h[mb], b_h[nb], acc2[mb][nb], 0, 0, 0);
                acc2[mb][nb] = __builtin_amdgcn_mfma_f32_16x16x32_bf16(a_h[mb], b_l[nb], acc2[mb][nb], 0, 0, 0);
                acc2[mb][nb] = __builtin_amdgcn_mfma_f32_16x16x32_bf16(a_l[mb], b_h[nb], acc2[mb][nb], 0, 0, 0);
            }
    }

    __syncthreads();   // all H reads done; region reused for P

    // -------- P -> LDS --------
    #pragma unroll
    for (int mb = 0; mb < 2; ++mb)
        #pragma unroll
        for (int nb = 0; nb < 2; ++nb) {
            const int col = w * 32 + nb * 16 + l16;
            #pragma unroll
            for (int r = 0; r < 4; ++r) {
                const int row = mb * 16 + g * 4 + r;
                P[row * P_STR + col] = acc2[mb][nb][r];
            }
        }

    __syncthreads();

    // -------- bias + LN + L2 normalize + store (verified epilogue) --------
    {
        const int tm = tid >> 5;               // rows tm*4..+4
        const int tn = tid & 31;               // cols tn*4
        float4 g4  = *reinterpret_cast<const float4*>(gam + tn * 4);
        float4 be4 = *reinterpret_cast<const float4*>(bet + tn * 4);
        float4 b24 = *reinterpret_cast<const float4*>(b2  + tn * 4);
        float gf[4]  = {g4.x, g4.y, g4.z, g4.w};
        float bf[4]  = {be4.x, be4.y, be4.z, be4.w};
        float b2f[4] = {b24.x, b24.y, b24.z, b24.w};

        #pragma unroll
        for (int i = 0; i < 4; ++i) {
            float4 pv = *reinterpret_cast<const float4*>(P + (tm * 4 + i) * P_STR + tn * 4);
            float v[4] = {pv.x, pv.y, pv.z, pv.w};
            float lsum = 0.f, lsq = 0.f;
            #pragma unroll
            for (int j = 0; j < 4; ++j) {
                v[j] += b2f[j];
                lsum += v[j];
                lsq  += v[j] * v[j];
            }
            #pragma unroll
            for (int m = 1; m < 32; m <<= 1) {
                lsum += __shfl_xor(lsum, m, 64);
                lsq  += __shfl_xor(lsq,  m, 64);
            }
            float mu   = lsum * (1.0f / PROJ);
            float var  = lsq  * (1.0f / PROJ) - mu * mu;
            float rstd = rsqrtf(var + 1e-5f);
            float l2 = 0.f;
            #pragma unroll
            for (int j = 0; j < 4; ++j) {
                v[j] = (v[j] - mu) * rstd * gf[j] + bf[j];
                l2 += v[j] * v[j];
            }
            #pragma unroll
            for (int m = 1; m < 32; m <<= 1) l2 += __shfl_xor(l2, m, 64);
            float rn = rsqrtf(l2);
            float4 o;
            o.x = v[0] * rn; o.y = v[1] * rn; o.z = v[2] * rn; o.w = v[3] * rn;
            *reinterpret_cast<float4*>(pool + (size_t)(row0 + tm * 4 + i) * PROJ + tn * 4) = o;
        }
    }
}

// ---------------------------------------------------------------------------
// Kernel B: per-row InfoNCE loss; 2 rows/wave, float4 loads, 32-lane reduce
// ---------------------------------------------------------------------------
__global__ __launch_bounds__(256, 4)
void loss_kernel(const float* __restrict__ pool, const int* __restrict__ nidx,
                 float* __restrict__ partials)
{
    const int wave = threadIdx.x >> 6;
    const int lane = threadIdx.x & 63;
    const int sub  = lane >> 5;            // 0/1: which row of the pair
    const int l32  = lane & 31;
    float local = 0.f;

    for (int b = blockIdx.x * 8 + wave * 2 + sub; b < NB; b += gridDim.x * 8) {
        const float4 av = *reinterpret_cast<const float4*>(pool + (size_t)b * PROJ + l32 * 4);
        const float4 pv = *reinterpret_cast<const float4*>(pool + (size_t)(b + NB) * PROJ + l32 * 4);
        float d[9];
        d[0] = av.x * pv.x + av.y * pv.y + av.z * pv.z + av.w * pv.w;
        #pragma unroll
        for (int k = 0; k < KNEG; k++) {
            const int idx = nidx[b * KNEG + k];
            const float4 nv = *reinterpret_cast<const float4*>(pool + (size_t)idx * PROJ + l32 * 4);
            d[k + 1] = av.x * nv.x + av.y * nv.y + av.z * nv.z + av.w * nv.w;
        }
        #pragma unroll
        for (int m = 1; m < 32; m <<= 1)
            #pragma unroll
            for (int t = 0; t < 9; t++) d[t] += __shfl_xor(d[t], m, 32);

        float pos = d[0] * TEMP_INV;
        float mx = pos;
        #pragma unroll
        for (int t = 1; t < 9; t++) mx = fmaxf(mx, d[t] * TEMP_INV);
        float se = 0.f;
        #pragma unroll
        for (int t = 0; t < 9; t++) se += __expf(d[t] * TEMP_INV - mx);
        float loss = -pos + mx + __logf(se);
        if (l32 == 0) local += loss;
    }

    local += __shfl_xor(local, 32, 64);    // combine the two sub-rows

    __shared__ float red[4];
    if (lane == 0) red[wave] = local;
    __syncthreads();
    if (threadIdx.x == 0)
        partials[blockIdx.x] = red[0] + red[1] + red[2] + red[3];
}

// ---------------------------------------------------------------------------
// Kernel C: final reduction -> mean
// ---------------------------------------------------------------------------
__global__ __launch_bounds__(256)
void reduce_kernel(const float* __restrict__ partials, float* __restrict__ out)
{
    const int tid = threadIdx.x;
    float s = 0.f;
    for (int i = tid; i < 4096; i += 256) s += partials[i];
    #pragma unroll
    for (int m = 1; m < 64; m <<= 1) s += __shfl_xor(s, m, 64);
    __shared__ float red[4];
    if ((tid & 63) == 0) red[tid >> 6] = s;
    __syncthreads();
    if (tid == 0)
        out[0] = (red[0] + red[1] + red[2] + red[3]) * (1.0f / NB);
}

// ---------------------------------------------------------------------------
extern "C" void kernel_launch(void* const* d_in, const int* in_sizes, int n_in,
                              void* d_out, int out_size, void* d_ws, size_t ws_size,
                              hipStream_t stream)
{
    const float* hs = (const float*)d_in[0];
    const float* ph = (const float*)d_in[1];
    const int*   ni = (const int*)  d_in[2];
    const float* W1 = (const float*)d_in[3];
    const float* b1 = (const float*)d_in[4];
    const float* W2 = (const float*)d_in[5];
    const float* b2 = (const float*)d_in[6];
    const float* gm = (const float*)d_in[7];
    const float* bt = (const float*)d_in[8];

    float* pool     = (float*)d_ws;                 // 2B*128 f32 = 67.1 MB
    float* partials = pool + (size_t)2 * NB * PROJ; // 4096 f32
    short* w1h = (short*)(partials + 4096);         // [256][512] bf16
    short* w1l = w1h + HID * MID;
    short* w2h = w1l + HID * MID;                   // [128][256] bf16
    short* w2l = w2h + MID * PROJ;
    float* out = (float*)d_out;

    prep_w_kernel<<<(HID * MID + 255) / 256, 256, 0, stream>>>(W1, w1h, w1l, MID, 9, HID * MID);
    prep_w_kernel<<<(MID * PROJ + 255) / 256, 256, 0, stream>>>(W2, w2h, w2l, PROJ, 8, MID * PROJ);

    proj_mfma<<<2 * NB / 32, 256, 0, stream>>>(hs, ph, w1h, w1l, w2h, w2l, b1, b2, gm, bt, pool);
    loss_kernel<<<4096, 256, 0, stream>>>(pool, ni, partials);
    reduce_kernel<<<1, 256, 0, stream>>>(partials, out);
}